// Round 6
// baseline (241.651 us; speedup 1.0000x reference)
//
#include <hip/hip_runtime.h>

typedef __attribute__((ext_vector_type(8))) __bf16 bf16x8;
typedef __attribute__((ext_vector_type(4))) float f32x4;
typedef unsigned short u16;
typedef unsigned int u32;

#define NB 524288
#define EPSI 1e-5f
#define NSHADOW 16   // sharded stat accumulators: 16 x 128 floats

__device__ __forceinline__ float bf2f(u16 h) {
    union { u32 u; float f; } cv; cv.u = ((u32)h) << 16; return cv.f;
}
__device__ __forceinline__ u16 f2bf(float f) {
    __bf16 b = (__bf16)f; return __builtin_bit_cast(u16, b);
}
__device__ __forceinline__ float ldany(const void* p, long i, int isf) {
    return isf ? ((const float*)p)[i] : bf2f(((const u16*)p)[i]);
}

// gelu_tanh = v * sigmoid(1.5957691*v*(1+0.044715 v^2)); |err| vs erf-gelu ~3e-4
__device__ __forceinline__ float fast_gelu(float v) {
    float t = 1.5957691216057308f * v * (1.0f + 0.044715f * v * v);
    float en = __expf(-t);
    return v * __builtin_amdgcn_rcpf(1.0f + en);
}

template<typename T>
__device__ __forceinline__ void load8f(const T* p, float* o);
template<>
__device__ __forceinline__ void load8f<__bf16>(const __bf16* p, float* o) {
    bf16x8 r = *reinterpret_cast<const bf16x8*>(p);
#pragma unroll
    for (int i = 0; i < 8; ++i) o[i] = (float)r[i];
}
template<>
__device__ __forceinline__ void load8f<float>(const float* p, float* o) {
    f32x4 a = *reinterpret_cast<const f32x4*>(p);
    f32x4 b = *reinterpret_cast<const f32x4*>(p + 4);
#pragma unroll
    for (int i = 0; i < 4; ++i) { o[i] = a[i]; o[4 + i] = b[i]; }
}

__device__ __forceinline__ bf16x8 loadfrag(const __bf16* p) {
    return *reinterpret_cast<const bf16x8*>(p);
}
__device__ __forceinline__ bf16x8 loadfrag(const float* p) {
    f32x4 a = *reinterpret_cast<const f32x4*>(p);
    f32x4 b = *reinterpret_cast<const f32x4*>(p + 4);
    bf16x8 r;
#pragma unroll
    for (int i = 0; i < 4; ++i) { r[i] = (__bf16)a[i]; r[4 + i] = (__bf16)b[i]; }
    return r;
}

// Per-wave dtype self-detect (f32-as-u16 low halves: ~25% have bf16-exp>=0xC0; true
// bf16 N(0,1): none). P(miss) < 1e-14 over 128 samples.
__device__ __forceinline__ int detect_isf(const void* x) {
    const int lane = threadIdx.x & 63;
    u32 w0 = ((const u32*)x)[lane];
    u32 w1 = ((const u32*)x)[64 + lane];
    int hit = ((((w0 >> 7) & 0xFFu) >= 0xC0u) || (((w1 >> 7) & 0xFFu) >= 0xC0u)) ? 1 : 0;
    return __ballot(hit) != 0ull;
}

// VALU-pipe rotation-add over each 16-lane row (DPP row_ror:N)
template<int CTRL>
__device__ __forceinline__ float dpp_rot_add(float v) {
    int s = __builtin_amdgcn_update_dpp(0, __builtin_bit_cast(int, v), CTRL, 0xF, 0xF, false);
    return v + __builtin_bit_cast(float, s);
}
__device__ __forceinline__ float row_reduce_add(float v) {
    v = dpp_rot_add<0x121>(v);   // row_ror:1
    v = dpp_rot_add<0x122>(v);   // row_ror:2
    v = dpp_rot_add<0x124>(v);   // row_ror:4
    v = dpp_rot_add<0x128>(v);   // row_ror:8
    return v;
}

// ---- stats (+pack): column sums/sumsq of h_pre = x @ w_in^T into 16 sharded copies
template<typename T>
__device__ __forceinline__ void stats_body(const T* __restrict__ x,
                                           const T* __restrict__ w_in,
                                           float* __restrict__ ws,
                                           float* __restrict__ red) {
    const int lane = threadIdx.x & 63;
    const int wave = threadIdx.x >> 6;
    const int c = lane & 15;
    const int q = lane >> 4;

    bf16x8 b1[4];
#pragma unroll
    for (int nt = 0; nt < 4; ++nt)
        b1[nt] = loadfrag(w_in + (nt * 16 + c) * 32 + q * 8);

    float accs[4][4], accq[4][4];
#pragma unroll
    for (int nt = 0; nt < 4; ++nt)
#pragma unroll
        for (int r = 0; r < 4; ++r) { accs[nt][r] = 0.f; accq[nt][r] = 0.f; }

    const int wid = blockIdx.x * 4 + wave;  // 0..8191, 64 rows each
    for (int t = 0; t < 4; ++t) {
        const long row0 = ((long)wid * 4 + t) * 16;
        bf16x8 a1 = loadfrag(x + (row0 + c) * 32 + q * 8);
#pragma unroll
        for (int nt = 0; nt < 4; ++nt) {
            f32x4 z = {0.f, 0.f, 0.f, 0.f};
            f32x4 acc = __builtin_amdgcn_mfma_f32_16x16x32_bf16(a1, b1[nt], z, 0, 0, 0);
#pragma unroll
            for (int r = 0; r < 4; ++r) {
                float v = acc[r];
                accs[nt][r] += v;
                accq[nt][r] += v * v;
            }
        }
    }
    for (int i = threadIdx.x; i < 128; i += 256) red[i] = 0.f;
    __syncthreads();
#pragma unroll
    for (int nt = 0; nt < 4; ++nt) {
        float s  = accs[nt][0] + accs[nt][1] + accs[nt][2] + accs[nt][3];
        float sq = accq[nt][0] + accq[nt][1] + accq[nt][2] + accq[nt][3];
        s  += __shfl_xor(s, 16);  s  += __shfl_xor(s, 32);
        sq += __shfl_xor(sq, 16); sq += __shfl_xor(sq, 32);
        if (q == 0) {
            atomicAdd(&red[nt * 16 + c], s);
            atomicAdd(&red[64 + nt * 16 + c], sq);
        }
    }
    __syncthreads();
    float* shard = ws + (blockIdx.x & (NSHADOW - 1)) * 128;
    for (int i = threadIdx.x; i < 128; i += 256) atomicAdd(&shard[i], red[i]);
}

__global__ __launch_bounds__(256) void stats_kernel(
    const void* x, const void* w_in, const void* w_fi, const void* b_fi,
    const void* w_fs, const void* b_fs, const void* w_lc, const void* b_lc,
    float* __restrict__ ws)
{
    const int isf = detect_isf(x);

    // pack W2 (96x64 bf16, u/v leaf-pairs folded): blocks 0..23; biases: block 24
    if (blockIdx.x < 24) {
        u16* W2p = (u16*)(ws + 2176);
        const int idx = blockIdx.x * 256 + threadIdx.x;   // 0..6143
        const int g = idx >> 6, f = idx & 63;
        float v = 0.f;
        if (g < 32)                 v = ldany(w_fi, (long)g * 64 + f, isf);
        else if (g < 64)            v = ldany(w_fs, (long)(g - 32) * 64 + f, isf);
        else if (g < 74)            v = ldany(w_lc, (long)(g - 64) * 64 + f, isf)
                                      + ldany(w_lc, (long)(g - 54) * 64 + f, isf);
        else if (g >= 80 && g < 90) v = ldany(w_lc, (long)(g - 60) * 64 + f, isf)
                                      + ldany(w_lc, (long)(g - 50) * 64 + f, isf);
        W2p[idx] = f2bf(v);
    } else if (blockIdx.x == 24 && threadIdx.x < 96) {
        float* biasP = ws + 2048;
        const int g = threadIdx.x;
        float v = 0.f;
        if (g < 32)                 v = ldany(b_fi, g, isf);
        else if (g < 64)            v = ldany(b_fs, g - 32, isf);
        else if (g < 74)            v = ldany(b_lc, g - 64, isf) + ldany(b_lc, g - 54, isf);
        else if (g >= 80 && g < 90) v = ldany(b_lc, g - 60, isf) + ldany(b_lc, g - 50, isf);
        biasP[g] = v;
    }

    __shared__ float red[128];
    if (isf) stats_body<float>((const float*)x, (const float*)w_in, ws, red);
    else     stats_body<__bf16>((const __bf16*)x, (const __bf16*)w_in, ws, red);
}

// ---- main: LDS-free compute. GEMM1 transposed (A=W1-rows permuted by phi, B=x^T) so
// C-layout output IS the A-fragment of GEMM2. phi(nt,m)=32(nt>>1)+8(m>>2)+4(nt&1)+(m&3).
template<typename T>
__device__ __forceinline__ void main_body(
    const T* __restrict__ x, const T* __restrict__ bn_g, const T* __restrict__ bn_b,
    const T* __restrict__ w_in, const float* __restrict__ ws,
    const float* __restrict__ sums, T* __restrict__ out)
{
    const int lane = threadIdx.x & 63;
    const int wave = threadIdx.x >> 6;
    const int c = lane & 15;
    const int q = lane >> 4;
    const float* biasP = ws + 2048;
    const u16* W2p = (const u16*)(ws + 2176);

    // A1-frags: row phi(nt,c), k=8q..8q+7, BN scale folded in (single bf16 rounding)
    bf16x8 b1[4];
#pragma unroll
    for (int nt = 0; nt < 4; ++nt) {
        const int row = 32 * (nt >> 1) + 8 * (c >> 2) + 4 * (nt & 1) + (c & 3);
        float mu  = sums[row] * (1.0f / NB);
        float var = fmaxf(sums[64 + row] * (1.0f / NB) - mu * mu, 0.0f);
        float s   = (float)bn_g[row] * rsqrtf(var + EPSI);
        float w8[8];
        load8f(w_in + row * 32 + q * 8, w8);
        bf16x8 f;
#pragma unroll
        for (int j = 0; j < 8; ++j) f[j] = (__bf16)(w8[j] * s);
        b1[nt] = f;
    }

    // per-element BN shift for feat phi(nt, 4q+r)
    float shift_t[4][4];
#pragma unroll
    for (int nt = 0; nt < 4; ++nt)
#pragma unroll
        for (int r = 0; r < 4; ++r) {
            const int ft = 32 * (nt >> 1) + 8 * q + 4 * (nt & 1) + r;
            float mu  = sums[ft] * (1.0f / NB);
            float var = fmaxf(sums[64 + ft] * (1.0f / NB) - mu * mu, 0.0f);
            float s   = (float)bn_g[ft] * rsqrtf(var + EPSI);
            shift_t[nt][r] = (float)bn_b[ft] - mu * s;
        }

    bf16x8 b2[6][2];
#pragma unroll
    for (int nt = 0; nt < 6; ++nt)
#pragma unroll
        for (int kt = 0; kt < 2; ++kt)
            b2[nt][kt] = *reinterpret_cast<const bf16x8*>(W2p + (nt * 16 + c) * 64 + kt * 32 + q * 8);

    const float bfi0 = biasP[c],      bfi1 = biasP[16 + c];
    const float bfs0 = biasP[32 + c], bfs1 = biasP[48 + c];
    const float bu   = biasP[64 + c], bv   = biasP[80 + c];

    const long gw = (long)blockIdx.x * 4 + wave;   // 0..8191, 64 rows each
#pragma unroll 2
    for (int t = 0; t < 4; ++t) {
        const long row0 = gw * 64 + (long)t * 16;
        // B-frag of GEMM1: B[k=8q+j][n=c] = x[row0+c][8q+j]
        bf16x8 a1 = loadfrag(x + (row0 + c) * 32 + q * 8);

        // epilogue x in C-layout (L1-hot, same lines as a1 across the wave)
        float xv0[4], xv1[4];
#pragma unroll
        for (int r = 0; r < 4; ++r) {
            xv0[r] = (float)x[(row0 + q * 4 + r) * 32 + c];
            xv1[r] = (float)x[(row0 + q * 4 + r) * 32 + 16 + c];
        }

        // GEMM1^T: lane(c,q) reg (nt,r) = s*h_pre[batch c][feat phi(nt,4q+r)]
        f32x4 h4[4];
#pragma unroll
        for (int nt = 0; nt < 4; ++nt) {
            f32x4 z = {0.f, 0.f, 0.f, 0.f};
            h4[nt] = __builtin_amdgcn_mfma_f32_16x16x32_bf16(b1[nt], a1, z, 0, 0, 0);
        }

        // shift + gelu; pack: a2_0[j=4nt+r]=g[nt][r] (nt 0..1), a2_1: nt 2..3
        bf16x8 a2_0, a2_1;
#pragma unroll
        for (int nt = 0; nt < 2; ++nt)
#pragma unroll
            for (int r = 0; r < 4; ++r) {
                a2_0[nt * 4 + r] = (__bf16)fast_gelu(h4[nt][r] + shift_t[nt][r]);
                a2_1[nt * 4 + r] = (__bf16)fast_gelu(h4[2 + nt][r] + shift_t[2 + nt][r]);
            }

        f32x4 acc[6];
#pragma unroll
        for (int nt = 0; nt < 6; ++nt) {
            f32x4 z = {0.f, 0.f, 0.f, 0.f};
            acc[nt] = __builtin_amdgcn_mfma_f32_16x16x32_bf16(a2_0, b2[nt][0], z, 0, 0, 0);
            acc[nt] = __builtin_amdgcn_mfma_f32_16x16x32_bf16(a2_1, b2[nt][1], acc[nt], 0, 0, 0);
        }

#pragma unroll
        for (int r = 0; r < 4; ++r) {
            // no max-subtraction: |fi| bounded << 87, f32 exp safe
            float e0  = __expf(acc[0][r] + bfi0);
            float e1  = __expf(acc[1][r] + bfi1);
            float fs0 = acc[2][r] + bfs0;
            float fs1 = acc[3][r] + bfs1;
            float es = row_reduce_add(e0 + e1);
            float dp = row_reduce_add(e0 * (xv0[r] - fs0) + e1 * (xv1[r] - fs1));
            float d  = dp * __builtin_amdgcn_rcpf(es);
            float sd = __builtin_amdgcn_rcpf(1.0f + __expf(-d));
            float uu = acc[4][r] + bu, vv = acc[5][r] + bv;
            float o = sd * (vv + sd * (uu - vv));  // sd^2*u + sd(1-sd)*v
            if (c < 10) out[(row0 + q * 4 + r) * 10 + c] = (T)o;
        }
    }
}

__global__ __launch_bounds__(256, 8) void main_kernel(
    const void* x, const void* bn_g, const void* bn_b, const void* w_in,
    float* ws, void* outv)
{
    // collapse the 16 sharded stat copies once per block
    __shared__ float sums[128];
    if (threadIdx.x < 128) {
        float s = 0.f;
#pragma unroll
        for (int k = 0; k < NSHADOW; ++k) s += ws[k * 128 + threadIdx.x];
        sums[threadIdx.x] = s;
    }
    __syncthreads();

    if (detect_isf(x))
        main_body<float>((const float*)x, (const float*)bn_g, (const float*)bn_b,
                         (const float*)w_in, ws, sums, (float*)outv);
    else
        main_body<__bf16>((const __bf16*)x, (const __bf16*)bn_g, (const __bf16*)bn_b,
                          (const __bf16*)w_in, ws, sums, (__bf16*)outv);
}

extern "C" void kernel_launch(void* const* d_in, const int* in_sizes, int n_in,
                              void* d_out, int out_size, void* d_ws, size_t ws_size,
                              hipStream_t stream) {
    float* ws = (float*)d_ws;
    hipMemsetAsync(d_ws, 0, NSHADOW * 128 * sizeof(float), stream);  // zero shard accumulators
    stats_kernel<<<2048, 256, 0, stream>>>(d_in[0], d_in[1], d_in[5], d_in[6],
                                           d_in[7], d_in[8], d_in[9], d_in[10], ws);
    main_kernel<<<2048, 256, 0, stream>>>(d_in[0], d_in[3], d_in[4], d_in[1], ws, d_out);
}

// Round 7
// 169.564 us; speedup vs baseline: 1.4251x; 1.4251x over previous
//
#include <hip/hip_runtime.h>

typedef __attribute__((ext_vector_type(8))) __bf16 bf16x8;
typedef __attribute__((ext_vector_type(4))) float f32x4;
typedef unsigned short u16;
typedef unsigned int u32;

#define NB 524288
#define EPSI 1e-5f
#define NSHADOW 16   // sharded stat accumulators: 16 x 128 floats

__device__ __forceinline__ float bf2f(u16 h) {
    union { u32 u; float f; } cv; cv.u = ((u32)h) << 16; return cv.f;
}
__device__ __forceinline__ u16 f2bf(float f) {
    __bf16 b = (__bf16)f; return __builtin_bit_cast(u16, b);
}
__device__ __forceinline__ float ldany(const void* p, long i, int isf) {
    return isf ? ((const float*)p)[i] : bf2f(((const u16*)p)[i]);
}

// gelu_tanh = v * sigmoid(1.5957691*v*(1+0.044715 v^2)); |err| vs erf-gelu ~3e-4
__device__ __forceinline__ float fast_gelu(float v) {
    float t = 1.5957691216057308f * v * (1.0f + 0.044715f * v * v);
    float en = __expf(-t);
    return v * __builtin_amdgcn_rcpf(1.0f + en);
}

template<typename T>
__device__ __forceinline__ void load8f(const T* p, float* o);
template<>
__device__ __forceinline__ void load8f<__bf16>(const __bf16* p, float* o) {
    bf16x8 r = *reinterpret_cast<const bf16x8*>(p);
#pragma unroll
    for (int i = 0; i < 8; ++i) o[i] = (float)r[i];
}
template<>
__device__ __forceinline__ void load8f<float>(const float* p, float* o) {
    f32x4 a = *reinterpret_cast<const f32x4*>(p);
    f32x4 b = *reinterpret_cast<const f32x4*>(p + 4);
#pragma unroll
    for (int i = 0; i < 4; ++i) { o[i] = a[i]; o[4 + i] = b[i]; }
}

__device__ __forceinline__ bf16x8 loadfrag(const __bf16* p) {
    return *reinterpret_cast<const bf16x8*>(p);
}
__device__ __forceinline__ bf16x8 loadfrag(const float* p) {
    f32x4 a = *reinterpret_cast<const f32x4*>(p);
    f32x4 b = *reinterpret_cast<const f32x4*>(p + 4);
    bf16x8 r;
#pragma unroll
    for (int i = 0; i < 4; ++i) { r[i] = (__bf16)a[i]; r[4 + i] = (__bf16)b[i]; }
    return r;
}

// Per-wave dtype self-detect (f32-as-u16 low halves: ~25% have bf16-exp>=0xC0; true
// bf16 N(0,1): none). P(miss) < 1e-14 over 128 samples.
__device__ __forceinline__ int detect_isf(const void* x) {
    const int lane = threadIdx.x & 63;
    u32 w0 = ((const u32*)x)[lane];
    u32 w1 = ((const u32*)x)[64 + lane];
    int hit = ((((w0 >> 7) & 0xFFu) >= 0xC0u) || (((w1 >> 7) & 0xFFu) >= 0xC0u)) ? 1 : 0;
    return __ballot(hit) != 0ull;
}

// VALU-pipe rotation-add over each 16-lane row (DPP row_ror:N)
template<int CTRL>
__device__ __forceinline__ float dpp_rot_add(float v) {
    int s = __builtin_amdgcn_update_dpp(0, __builtin_bit_cast(int, v), CTRL, 0xF, 0xF, false);
    return v + __builtin_bit_cast(float, s);
}
__device__ __forceinline__ float row_reduce_add(float v) {
    v = dpp_rot_add<0x121>(v);   // row_ror:1
    v = dpp_rot_add<0x122>(v);   // row_ror:2
    v = dpp_rot_add<0x124>(v);   // row_ror:4
    v = dpp_rot_add<0x128>(v);   // row_ror:8
    return v;
}

// ---- stats (+pack): column sums/sumsq of h_pre = x @ w_in^T into 16 sharded copies
template<typename T>
__device__ __forceinline__ void stats_body(const T* __restrict__ x,
                                           const T* __restrict__ w_in,
                                           float* __restrict__ ws,
                                           float* __restrict__ red) {
    const int lane = threadIdx.x & 63;
    const int wave = threadIdx.x >> 6;
    const int c = lane & 15;
    const int q = lane >> 4;

    bf16x8 b1[4];
#pragma unroll
    for (int nt = 0; nt < 4; ++nt)
        b1[nt] = loadfrag(w_in + (nt * 16 + c) * 32 + q * 8);

    float accs[4][4], accq[4][4];
#pragma unroll
    for (int nt = 0; nt < 4; ++nt)
#pragma unroll
        for (int r = 0; r < 4; ++r) { accs[nt][r] = 0.f; accq[nt][r] = 0.f; }

    const int wid = blockIdx.x * 4 + wave;  // 0..8191, 64 rows each
    for (int t = 0; t < 4; ++t) {
        const long row0 = ((long)wid * 4 + t) * 16;
        bf16x8 a1 = loadfrag(x + (row0 + c) * 32 + q * 8);
#pragma unroll
        for (int nt = 0; nt < 4; ++nt) {
            f32x4 z = {0.f, 0.f, 0.f, 0.f};
            f32x4 acc = __builtin_amdgcn_mfma_f32_16x16x32_bf16(a1, b1[nt], z, 0, 0, 0);
#pragma unroll
            for (int r = 0; r < 4; ++r) {
                float v = acc[r];
                accs[nt][r] += v;
                accq[nt][r] += v * v;
            }
        }
    }
    for (int i = threadIdx.x; i < 128; i += 256) red[i] = 0.f;
    __syncthreads();
#pragma unroll
    for (int nt = 0; nt < 4; ++nt) {
        float s  = accs[nt][0] + accs[nt][1] + accs[nt][2] + accs[nt][3];
        float sq = accq[nt][0] + accq[nt][1] + accq[nt][2] + accq[nt][3];
        s  += __shfl_xor(s, 16);  s  += __shfl_xor(s, 32);
        sq += __shfl_xor(sq, 16); sq += __shfl_xor(sq, 32);
        if (q == 0) {
            atomicAdd(&red[nt * 16 + c], s);
            atomicAdd(&red[64 + nt * 16 + c], sq);
        }
    }
    __syncthreads();
    float* shard = ws + (blockIdx.x & (NSHADOW - 1)) * 128;
    for (int i = threadIdx.x; i < 128; i += 256) atomicAdd(&shard[i], red[i]);
}

__global__ __launch_bounds__(256) void stats_kernel(
    const void* x, const void* w_in, const void* w_fi, const void* b_fi,
    const void* w_fs, const void* b_fs, const void* w_lc, const void* b_lc,
    float* __restrict__ ws)
{
    const int isf = detect_isf(x);

    // pack W2 (96x64 bf16, u/v leaf-pairs folded): blocks 0..23; biases: block 24
    if (blockIdx.x < 24) {
        u16* W2p = (u16*)(ws + 2176);
        const int idx = blockIdx.x * 256 + threadIdx.x;   // 0..6143
        const int g = idx >> 6, f = idx & 63;
        float v = 0.f;
        if (g < 32)                 v = ldany(w_fi, (long)g * 64 + f, isf);
        else if (g < 64)            v = ldany(w_fs, (long)(g - 32) * 64 + f, isf);
        else if (g < 74)            v = ldany(w_lc, (long)(g - 64) * 64 + f, isf)
                                      + ldany(w_lc, (long)(g - 54) * 64 + f, isf);
        else if (g >= 80 && g < 90) v = ldany(w_lc, (long)(g - 60) * 64 + f, isf)
                                      + ldany(w_lc, (long)(g - 50) * 64 + f, isf);
        W2p[idx] = f2bf(v);
    } else if (blockIdx.x == 24 && threadIdx.x < 96) {
        float* biasP = ws + 2048;
        const int g = threadIdx.x;
        float v = 0.f;
        if (g < 32)                 v = ldany(b_fi, g, isf);
        else if (g < 64)            v = ldany(b_fs, g - 32, isf);
        else if (g < 74)            v = ldany(b_lc, g - 64, isf) + ldany(b_lc, g - 54, isf);
        else if (g >= 80 && g < 90) v = ldany(b_lc, g - 60, isf) + ldany(b_lc, g - 50, isf);
        biasP[g] = v;
    }

    __shared__ float red[128];
    if (isf) stats_body<float>((const float*)x, (const float*)w_in, ws, red);
    else     stats_body<__bf16>((const __bf16*)x, (const __bf16*)w_in, ws, red);
}

// ---- main: LDS-free compute. GEMM1 transposed (A=W1-rows permuted by phi, B=x^T) so
// C-layout output IS the A-fragment of GEMM2. phi(nt,m)=32(nt>>1)+8(m>>2)+4(nt&1)+(m&3).
template<typename T>
__device__ __forceinline__ void main_body(
    const T* __restrict__ x, const T* __restrict__ bn_g, const T* __restrict__ bn_b,
    const T* __restrict__ w_in, const float* __restrict__ ws,
    const float* __restrict__ sums, T* __restrict__ out)
{
    const int lane = threadIdx.x & 63;
    const int wave = threadIdx.x >> 6;
    const int c = lane & 15;
    const int q = lane >> 4;
    const float* biasP = ws + 2048;
    const u16* W2p = (const u16*)(ws + 2176);

    // A1-frags: row phi(nt,c), k=8q..8q+7, BN scale folded in (single bf16 rounding)
    bf16x8 b1[4];
#pragma unroll
    for (int nt = 0; nt < 4; ++nt) {
        const int row = 32 * (nt >> 1) + 8 * (c >> 2) + 4 * (nt & 1) + (c & 3);
        float mu  = sums[row] * (1.0f / NB);
        float var = fmaxf(sums[64 + row] * (1.0f / NB) - mu * mu, 0.0f);
        float s   = (float)bn_g[row] * rsqrtf(var + EPSI);
        float w8[8];
        load8f(w_in + row * 32 + q * 8, w8);
        bf16x8 f;
#pragma unroll
        for (int j = 0; j < 8; ++j) f[j] = (__bf16)(w8[j] * s);
        b1[nt] = f;
    }

    // per-element BN shift for feat phi(nt, 4q+r)
    float shift_t[4][4];
#pragma unroll
    for (int nt = 0; nt < 4; ++nt)
#pragma unroll
        for (int r = 0; r < 4; ++r) {
            const int ft = 32 * (nt >> 1) + 8 * q + 4 * (nt & 1) + r;
            float mu  = sums[ft] * (1.0f / NB);
            float var = fmaxf(sums[64 + ft] * (1.0f / NB) - mu * mu, 0.0f);
            float s   = (float)bn_g[ft] * rsqrtf(var + EPSI);
            shift_t[nt][r] = (float)bn_b[ft] - mu * s;
        }

    bf16x8 b2[6][2];
#pragma unroll
    for (int nt = 0; nt < 6; ++nt)
#pragma unroll
        for (int kt = 0; kt < 2; ++kt)
            b2[nt][kt] = *reinterpret_cast<const bf16x8*>(W2p + (nt * 16 + c) * 64 + kt * 32 + q * 8);

    const float bfi0 = biasP[c],      bfi1 = biasP[16 + c];
    const float bfs0 = biasP[32 + c], bfs1 = biasP[48 + c];
    const float bu   = biasP[64 + c], bv   = biasP[80 + c];

    const long gw = (long)blockIdx.x * 4 + wave;   // 0..8191, 64 rows each
#pragma unroll 2
    for (int t = 0; t < 4; ++t) {
        const long row0 = gw * 64 + (long)t * 16;
        // B-frag of GEMM1: B[k=8q+j][n=c] = x[row0+c][8q+j]
        bf16x8 a1 = loadfrag(x + (row0 + c) * 32 + q * 8);

        // epilogue x in C-layout (L1-hot, same lines as a1 across the wave)
        float xv0[4], xv1[4];
#pragma unroll
        for (int r = 0; r < 4; ++r) {
            xv0[r] = (float)x[(row0 + q * 4 + r) * 32 + c];
            xv1[r] = (float)x[(row0 + q * 4 + r) * 32 + 16 + c];
        }

        // GEMM1^T: lane(c,q) reg (nt,r) = s*h_pre[batch c][feat phi(nt,4q+r)]
        f32x4 h4[4];
#pragma unroll
        for (int nt = 0; nt < 4; ++nt) {
            f32x4 z = {0.f, 0.f, 0.f, 0.f};
            h4[nt] = __builtin_amdgcn_mfma_f32_16x16x32_bf16(b1[nt], a1, z, 0, 0, 0);
        }

        // shift + gelu; pack: a2_0[j=4nt+r]=g[nt][r] (nt 0..1), a2_1: nt 2..3
        bf16x8 a2_0, a2_1;
#pragma unroll
        for (int nt = 0; nt < 2; ++nt)
#pragma unroll
            for (int r = 0; r < 4; ++r) {
                a2_0[nt * 4 + r] = (__bf16)fast_gelu(h4[nt][r] + shift_t[nt][r]);
                a2_1[nt * 4 + r] = (__bf16)fast_gelu(h4[2 + nt][r] + shift_t[2 + nt][r]);
            }

        f32x4 acc[6];
#pragma unroll
        for (int nt = 0; nt < 6; ++nt) {
            f32x4 z = {0.f, 0.f, 0.f, 0.f};
            acc[nt] = __builtin_amdgcn_mfma_f32_16x16x32_bf16(a2_0, b2[nt][0], z, 0, 0, 0);
            acc[nt] = __builtin_amdgcn_mfma_f32_16x16x32_bf16(a2_1, b2[nt][1], acc[nt], 0, 0, 0);
        }

#pragma unroll
        for (int r = 0; r < 4; ++r) {
            // no max-subtraction: |fi| bounded << 87, f32 exp safe
            float e0  = __expf(acc[0][r] + bfi0);
            float e1  = __expf(acc[1][r] + bfi1);
            float fs0 = acc[2][r] + bfs0;
            float fs1 = acc[3][r] + bfs1;
            float es = row_reduce_add(e0 + e1);
            float dp = row_reduce_add(e0 * (xv0[r] - fs0) + e1 * (xv1[r] - fs1));
            float d  = dp * __builtin_amdgcn_rcpf(es);
            float sd = __builtin_amdgcn_rcpf(1.0f + __expf(-d));
            float uu = acc[4][r] + bu, vv = acc[5][r] + bv;
            float o = sd * (vv + sd * (uu - vv));  // sd^2*u + sd(1-sd)*v
            if (c < 10) out[(row0 + q * 4 + r) * 10 + c] = (T)o;
        }
    }
}

// (256,4): VGPR=64 codegen (no spills, verified R5); HW allows 8 waves/SIMD at 64 VGPR,
// so residency comes from grid size, not the bound. (256,8) forces VGPR<=32 -> 430 MB
// of scratch spill traffic (measured R6) -- never do that.
__global__ __launch_bounds__(256, 4) void main_kernel(
    const void* x, const void* bn_g, const void* bn_b, const void* w_in,
    float* ws, void* outv)
{
    // collapse the 16 sharded stat copies once per block
    __shared__ float sums[128];
    if (threadIdx.x < 128) {
        float s = 0.f;
#pragma unroll
        for (int k = 0; k < NSHADOW; ++k) s += ws[k * 128 + threadIdx.x];
        sums[threadIdx.x] = s;
    }
    __syncthreads();

    if (detect_isf(x))
        main_body<float>((const float*)x, (const float*)bn_g, (const float*)bn_b,
                         (const float*)w_in, ws, sums, (float*)outv);
    else
        main_body<__bf16>((const __bf16*)x, (const __bf16*)bn_g, (const __bf16*)bn_b,
                          (const __bf16*)w_in, ws, sums, (__bf16*)outv);
}

extern "C" void kernel_launch(void* const* d_in, const int* in_sizes, int n_in,
                              void* d_out, int out_size, void* d_ws, size_t ws_size,
                              hipStream_t stream) {
    float* ws = (float*)d_ws;
    hipMemsetAsync(d_ws, 0, NSHADOW * 128 * sizeof(float), stream);  // zero shard accumulators
    stats_kernel<<<2048, 256, 0, stream>>>(d_in[0], d_in[1], d_in[5], d_in[6],
                                           d_in[7], d_in[8], d_in[9], d_in[10], ws);
    main_kernel<<<2048, 256, 0, stream>>>(d_in[0], d_in[3], d_in[4], d_in[1], ws, d_out);
}

// Round 8
// 155.603 us; speedup vs baseline: 1.5530x; 1.0897x over previous
//
#include <hip/hip_runtime.h>

typedef __attribute__((ext_vector_type(8))) __bf16 bf16x8;
typedef __attribute__((ext_vector_type(4))) float f32x4;
typedef unsigned short u16;
typedef unsigned int u32;

#define NB 524288
#define EPSI 1e-5f
#define NSHADOW 16   // sharded stat accumulators: 16 x 128 floats

__device__ __forceinline__ float bf2f(u16 h) {
    union { u32 u; float f; } cv; cv.u = ((u32)h) << 16; return cv.f;
}
__device__ __forceinline__ u16 f2bf(float f) {
    __bf16 b = (__bf16)f; return __builtin_bit_cast(u16, b);
}
__device__ __forceinline__ float ldany(const void* p, long i, int isf) {
    return isf ? ((const float*)p)[i] : bf2f(((const u16*)p)[i]);
}

// gelu_tanh = v * sigmoid(1.5957691*v*(1+0.044715 v^2)); |err| vs erf-gelu ~3e-4
__device__ __forceinline__ float fast_gelu(float v) {
    float t = 1.5957691216057308f * v * (1.0f + 0.044715f * v * v);
    float en = __expf(-t);
    return v * __builtin_amdgcn_rcpf(1.0f + en);
}

template<typename T>
__device__ __forceinline__ void load8f(const T* p, float* o);
template<>
__device__ __forceinline__ void load8f<__bf16>(const __bf16* p, float* o) {
    bf16x8 r = *reinterpret_cast<const bf16x8*>(p);
#pragma unroll
    for (int i = 0; i < 8; ++i) o[i] = (float)r[i];
}
template<>
__device__ __forceinline__ void load8f<float>(const float* p, float* o) {
    f32x4 a = *reinterpret_cast<const f32x4*>(p);
    f32x4 b = *reinterpret_cast<const f32x4*>(p + 4);
#pragma unroll
    for (int i = 0; i < 4; ++i) { o[i] = a[i]; o[4 + i] = b[i]; }
}

__device__ __forceinline__ bf16x8 loadfrag(const __bf16* p) {
    return *reinterpret_cast<const bf16x8*>(p);
}
__device__ __forceinline__ bf16x8 loadfrag(const float* p) {
    f32x4 a = *reinterpret_cast<const f32x4*>(p);
    f32x4 b = *reinterpret_cast<const f32x4*>(p + 4);
    bf16x8 r;
#pragma unroll
    for (int i = 0; i < 4; ++i) { r[i] = (__bf16)a[i]; r[4 + i] = (__bf16)b[i]; }
    return r;
}

// Per-wave dtype self-detect (f32-as-u16 low halves: ~25% have bf16-exp>=0xC0; true
// bf16 N(0,1): none). P(miss) < 1e-14 over 128 samples.
__device__ __forceinline__ int detect_isf(const void* x) {
    const int lane = threadIdx.x & 63;
    u32 w0 = ((const u32*)x)[lane];
    u32 w1 = ((const u32*)x)[64 + lane];
    int hit = ((((w0 >> 7) & 0xFFu) >= 0xC0u) || (((w1 >> 7) & 0xFFu) >= 0xC0u)) ? 1 : 0;
    return __ballot(hit) != 0ull;
}

// VALU-pipe rotation-add over each 16-lane row (DPP row_ror:N)
template<int CTRL>
__device__ __forceinline__ float dpp_rot_add(float v) {
    int s = __builtin_amdgcn_update_dpp(0, __builtin_bit_cast(int, v), CTRL, 0xF, 0xF, false);
    return v + __builtin_bit_cast(float, s);
}
__device__ __forceinline__ float row_reduce_add(float v) {
    v = dpp_rot_add<0x121>(v);   // row_ror:1
    v = dpp_rot_add<0x122>(v);   // row_ror:2
    v = dpp_rot_add<0x124>(v);   // row_ror:4
    v = dpp_rot_add<0x128>(v);   // row_ror:8
    return v;
}

// ---- stats (+pack): column sums/sumsq of h_pre = x @ w_in^T into 16 sharded copies
template<typename T>
__device__ __forceinline__ void stats_body(const T* __restrict__ x,
                                           const T* __restrict__ w_in,
                                           float* __restrict__ ws,
                                           float* __restrict__ red) {
    const int lane = threadIdx.x & 63;
    const int wave = threadIdx.x >> 6;
    const int c = lane & 15;
    const int q = lane >> 4;

    bf16x8 b1[4];
#pragma unroll
    for (int nt = 0; nt < 4; ++nt)
        b1[nt] = loadfrag(w_in + (nt * 16 + c) * 32 + q * 8);

    float accs[4][4], accq[4][4];
#pragma unroll
    for (int nt = 0; nt < 4; ++nt)
#pragma unroll
        for (int r = 0; r < 4; ++r) { accs[nt][r] = 0.f; accq[nt][r] = 0.f; }

    const int wid = blockIdx.x * 4 + wave;  // 0..8191, 64 rows each
    for (int t = 0; t < 4; ++t) {
        const long row0 = ((long)wid * 4 + t) * 16;
        bf16x8 a1 = loadfrag(x + (row0 + c) * 32 + q * 8);
#pragma unroll
        for (int nt = 0; nt < 4; ++nt) {
            f32x4 z = {0.f, 0.f, 0.f, 0.f};
            f32x4 acc = __builtin_amdgcn_mfma_f32_16x16x32_bf16(a1, b1[nt], z, 0, 0, 0);
#pragma unroll
            for (int r = 0; r < 4; ++r) {
                float v = acc[r];
                accs[nt][r] += v;
                accq[nt][r] += v * v;
            }
        }
    }
    for (int i = threadIdx.x; i < 128; i += 256) red[i] = 0.f;
    __syncthreads();
#pragma unroll
    for (int nt = 0; nt < 4; ++nt) {
        float s  = accs[nt][0] + accs[nt][1] + accs[nt][2] + accs[nt][3];
        float sq = accq[nt][0] + accq[nt][1] + accq[nt][2] + accq[nt][3];
        s  += __shfl_xor(s, 16);  s  += __shfl_xor(s, 32);
        sq += __shfl_xor(sq, 16); sq += __shfl_xor(sq, 32);
        if (q == 0) {
            atomicAdd(&red[nt * 16 + c], s);
            atomicAdd(&red[64 + nt * 16 + c], sq);
        }
    }
    __syncthreads();
    float* shard = ws + (blockIdx.x & (NSHADOW - 1)) * 128;
    for (int i = threadIdx.x; i < 128; i += 256) atomicAdd(&shard[i], red[i]);
}

__global__ __launch_bounds__(256) void stats_kernel(
    const void* x, const void* w_in, const void* w_fi, const void* b_fi,
    const void* w_fs, const void* b_fs, const void* w_lc, const void* b_lc,
    float* __restrict__ ws)
{
    const int isf = detect_isf(x);

    // pack W2 (96x64 bf16, u/v leaf-pairs folded): blocks 0..23; biases: block 24
    if (blockIdx.x < 24) {
        u16* W2p = (u16*)(ws + 2176);
        const int idx = blockIdx.x * 256 + threadIdx.x;   // 0..6143
        const int g = idx >> 6, f = idx & 63;
        float v = 0.f;
        if (g < 32)                 v = ldany(w_fi, (long)g * 64 + f, isf);
        else if (g < 64)            v = ldany(w_fs, (long)(g - 32) * 64 + f, isf);
        else if (g < 74)            v = ldany(w_lc, (long)(g - 64) * 64 + f, isf)
                                      + ldany(w_lc, (long)(g - 54) * 64 + f, isf);
        else if (g >= 80 && g < 90) v = ldany(w_lc, (long)(g - 60) * 64 + f, isf)
                                      + ldany(w_lc, (long)(g - 50) * 64 + f, isf);
        W2p[idx] = f2bf(v);
    } else if (blockIdx.x == 24 && threadIdx.x < 96) {
        float* biasP = ws + 2048;
        const int g = threadIdx.x;
        float v = 0.f;
        if (g < 32)                 v = ldany(b_fi, g, isf);
        else if (g < 64)            v = ldany(b_fs, g - 32, isf);
        else if (g < 74)            v = ldany(b_lc, g - 64, isf) + ldany(b_lc, g - 54, isf);
        else if (g >= 80 && g < 90) v = ldany(b_lc, g - 60, isf) + ldany(b_lc, g - 50, isf);
        biasP[g] = v;
    }

    __shared__ float red[128];
    if (isf) stats_body<float>((const float*)x, (const float*)w_in, ws, red);
    else     stats_body<__bf16>((const __bf16*)x, (const __bf16*)w_in, ws, red);
}

// ---- main: all weight state staged in block LDS (frees ~80 unified regs/wave ->
// target 6-8 waves/SIMD). GEMM1 transposed (A=scaled-W1 rows permuted by phi, B=x^T)
// so C-layout output IS the A-fragment of GEMM2. phi(nt,m)=32(nt>>1)+8(m>>2)+4(nt&1)+(m&3).
template<typename T>
__device__ __forceinline__ void main_body(
    const T* __restrict__ x, const T* __restrict__ bn_g, const T* __restrict__ bn_b,
    const T* __restrict__ w_in, const float* __restrict__ ws, T* __restrict__ out,
    float* __restrict__ sums, float* __restrict__ shs,
    u16* __restrict__ w1s, u16* __restrict__ w2s)
{
    const int tid = threadIdx.x;
    const int lane = tid & 63;
    const int wave = tid >> 6;
    const int c = lane & 15;
    const int q = lane >> 4;
    const float* biasP = ws + 2048;

    // collapse the 16 sharded stat copies
    if (tid < 128) {
        float s = 0.f;
#pragma unroll
        for (int k = 0; k < NSHADOW; ++k) s += ws[k * 128 + tid];
        sums[tid] = s;
    }
    __syncthreads();

    // stage scaled-W1 fragments: slot tid -> (nt=tid>>6, lane=tid&63), 16B each
    {
        const int nt = tid >> 6, l = tid & 63, cc = l & 15, qq = l >> 4;
        const int row = 32 * (nt >> 1) + 8 * (cc >> 2) + 4 * (nt & 1) + (cc & 3);
        float mu  = sums[row] * (1.0f / NB);
        float var = fmaxf(sums[64 + row] * (1.0f / NB) - mu * mu, 0.0f);
        float s   = (float)bn_g[row] * rsqrtf(var + EPSI);
        float w8[8];
        load8f(w_in + row * 32 + qq * 8, w8);
        bf16x8 f;
#pragma unroll
        for (int j = 0; j < 8; ++j) f[j] = (__bf16)(w8[j] * s);
        *reinterpret_cast<bf16x8*>(w1s + tid * 8) = f;
    }
    // BN shifts: shs[q*16 + nt*4 + r] = shift(phi(nt,4q+r)); tid encodes (q,nt,r)
    if (tid < 64) {
        const int qq = tid >> 4, nt = (tid >> 2) & 3, r = tid & 3;
        const int ft = 32 * (nt >> 1) + 8 * qq + 4 * (nt & 1) + r;
        float mu  = sums[ft] * (1.0f / NB);
        float var = fmaxf(sums[64 + ft] * (1.0f / NB) - mu * mu, 0.0f);
        float s   = (float)bn_g[ft] * rsqrtf(var + EPSI);
        shs[tid] = (float)bn_b[ft] - mu * s;
    }
    // stage W2 fragments: 768 slots of 16B, slot k=(frag f=nt*2+kt)*64+lane
    {
        const u32* W2p32 = (const u32*)(ws + 2176);
        for (int k = tid; k < 768; k += 256) {
            const int f = k >> 6, l = k & 63, cc = l & 15, qq = l >> 4;
            const int nt = f >> 1, kt = f & 1;
            const u32* src = W2p32 + ((nt * 16 + cc) * 64 + kt * 32 + qq * 8) / 2;
            u32* dst = (u32*)(w2s + k * 8);
            dst[0] = src[0]; dst[1] = src[1]; dst[2] = src[2]; dst[3] = src[3];
        }
    }
    __syncthreads();

    const float bfi0 = biasP[c],      bfi1 = biasP[16 + c];
    const float bfs0 = biasP[32 + c], bfs1 = biasP[48 + c];
    const float bu   = biasP[64 + c], bv   = biasP[80 + c];

    const long gw = (long)blockIdx.x * 4 + wave;   // 0..16383, 32 rows each
#pragma unroll 2
    for (int t = 0; t < 2; ++t) {
        // opaque zero offset: stops the compiler hoisting LDS reads back into
        // persistent registers across tiles (the whole point of LDS staging)
        u32 tweak = 0;
        asm volatile("" : "+v"(tweak));
        const u16* w1b = w1s + tweak;
        const u16* w2b = w2s + tweak;
        const float* shb = shs + tweak;

        const long row0 = gw * 32 + (long)t * 16;
        // B-frag of GEMM1: B[k=8q+j][n=c] = x[row0+c][8q+j]
        bf16x8 a1 = loadfrag(x + (row0 + c) * 32 + q * 8);

        // epilogue x in C-layout (L1-hot, same lines as a1 across the wave)
        float xv0[4], xv1[4];
#pragma unroll
        for (int r = 0; r < 4; ++r) {
            xv0[r] = (float)x[(row0 + q * 4 + r) * 32 + c];
            xv1[r] = (float)x[(row0 + q * 4 + r) * 32 + 16 + c];
        }

        // GEMM1^T: lane(c,q) reg (nt,r) = s*h_pre[batch c][feat phi(nt,4q+r)]
        f32x4 h4[4];
#pragma unroll
        for (int nt = 0; nt < 4; ++nt) {
            bf16x8 b1f = *reinterpret_cast<const bf16x8*>(w1b + (nt * 64 + lane) * 8);
            f32x4 z = {0.f, 0.f, 0.f, 0.f};
            h4[nt] = __builtin_amdgcn_mfma_f32_16x16x32_bf16(b1f, a1, z, 0, 0, 0);
        }

        // shift + gelu; pack: a2_0[j=4nt+r]=g[nt][r] (nt 0..1), a2_1: nt 2..3
        bf16x8 a2_0, a2_1;
#pragma unroll
        for (int nt = 0; nt < 2; ++nt) {
            f32x4 shA = *reinterpret_cast<const f32x4*>(shb + q * 16 + nt * 4);
            f32x4 shB = *reinterpret_cast<const f32x4*>(shb + q * 16 + (2 + nt) * 4);
#pragma unroll
            for (int r = 0; r < 4; ++r) {
                a2_0[nt * 4 + r] = (__bf16)fast_gelu(h4[nt][r] + shA[r]);
                a2_1[nt * 4 + r] = (__bf16)fast_gelu(h4[2 + nt][r] + shB[r]);
            }
        }

        f32x4 acc[6];
#pragma unroll
        for (int nt = 0; nt < 6; ++nt) {
            bf16x8 f0 = *reinterpret_cast<const bf16x8*>(w2b + ((nt * 2 + 0) * 64 + lane) * 8);
            bf16x8 f1 = *reinterpret_cast<const bf16x8*>(w2b + ((nt * 2 + 1) * 64 + lane) * 8);
            f32x4 z = {0.f, 0.f, 0.f, 0.f};
            acc[nt] = __builtin_amdgcn_mfma_f32_16x16x32_bf16(a2_0, f0, z, 0, 0, 0);
            acc[nt] = __builtin_amdgcn_mfma_f32_16x16x32_bf16(a2_1, f1, acc[nt], 0, 0, 0);
        }

#pragma unroll
        for (int r = 0; r < 4; ++r) {
            // no max-subtraction: |fi| bounded << 87, f32 exp safe
            float e0  = __expf(acc[0][r] + bfi0);
            float e1  = __expf(acc[1][r] + bfi1);
            float fs0 = acc[2][r] + bfs0;
            float fs1 = acc[3][r] + bfs1;
            float es = row_reduce_add(e0 + e1);
            float dp = row_reduce_add(e0 * (xv0[r] - fs0) + e1 * (xv1[r] - fs1));
            float d  = dp * __builtin_amdgcn_rcpf(es);
            float sd = __builtin_amdgcn_rcpf(1.0f + __expf(-d));
            float uu = acc[4][r] + bu, vv = acc[5][r] + bv;
            float o = sd * (vv + sd * (uu - vv));  // sd^2*u + sd(1-sd)*v
            if (c < 10) out[(row0 + q * 4 + r) * 10 + c] = (T)o;
        }
    }
}

// (256,4): reg cap 128 (not binding, target ~70-80 unified). Actual occupancy =
// 512/actual_regs. (256,8) forces VGPR<=32 -> 430 MB spill traffic (measured R6).
__global__ __launch_bounds__(256, 4) void main_kernel(
    const void* x, const void* bn_g, const void* bn_b, const void* w_in,
    float* ws, void* outv)
{
    __shared__ float sums[128];
    __shared__ float shs[64];
    __shared__ __attribute__((aligned(16))) u16 w1s[4 * 64 * 8];    // 4 KB
    __shared__ __attribute__((aligned(16))) u16 w2s[12 * 64 * 8];   // 12 KB

    if (detect_isf(x))
        main_body<float>((const float*)x, (const float*)bn_g, (const float*)bn_b,
                         (const float*)w_in, ws, (float*)outv, sums, shs, w1s, w2s);
    else
        main_body<__bf16>((const __bf16*)x, (const __bf16*)bn_g, (const __bf16*)bn_b,
                          (const __bf16*)w_in, ws, (__bf16*)outv, sums, shs, w1s, w2s);
}

extern "C" void kernel_launch(void* const* d_in, const int* in_sizes, int n_in,
                              void* d_out, int out_size, void* d_ws, size_t ws_size,
                              hipStream_t stream) {
    float* ws = (float*)d_ws;
    hipMemsetAsync(d_ws, 0, NSHADOW * 128 * sizeof(float), stream);  // zero shard accumulators
    stats_kernel<<<2048, 256, 0, stream>>>(d_in[0], d_in[1], d_in[5], d_in[6],
                                           d_in[7], d_in[8], d_in[9], d_in[10], ws);
    main_kernel<<<4096, 256, 0, stream>>>(d_in[0], d_in[3], d_in[4], d_in[1], ws, d_out);
}